// Round 6
// baseline (223.029 us; speedup 1.0000x reference)
//
#include <hip/hip_runtime.h>
#include <hip/hip_bf16.h>

// HistogramLoss: two [32,3,512,512] fp32 inputs, per-(B,C) 64-bin histogram
// over [0,1], row-normalized (row count exactly 2^18), L1 mean of diff.
//
// R6: pure per-LANE register histogram. Evidence so far: LDS atomics are a
// ~80us wall (~62cy per wave ds_add, layout-independent - R1/R5); LDS RMW is
// latency-chain bound (R3); ballots cost 74 wave-instr/64elem (R2/R4).
// Here each lane counts its OWN elements into 8 VGPRs of 4-bit packed
// counters (nibble=bin): inc64 = 1ull<<((bin*4)&63), routed by 4
// cmp/cndmask/add pairs = ~26 wave-instr per 64 elements, zero DS ops, zero
// cross-lane traffic. Flush nibbles->byte accumulators (16 VGPRs, max
// 128/bin/lane < 256) every 12 elements. Epilogue: transposed LDS byte
// matrix, conflict-free b128 reads. Exact integer counting (absmax 0).

#define HW        262144             // 512*512 = 2^18
#define ROWS      96                 // B*C per image
#define NBINS     64
#define BPR       8                  // blocks per row
#define CHUNK     (HW / BPR)         // 32768 elements per block
#define THREADS   256
#define F4_ITERS  (CHUNK / 4 / THREADS)  // 32 float4 per thread (128 elems)
#define NBLOCKS   (2 * ROWS * BPR)   // 1536
#define TP        260                // transpose pitch (words); 260%32=4

__device__ __forceinline__ void bump(unsigned c[8], float x) {
    int bin = min((int)(x * 64.0f), 63);
    // one nonzero nibble at position (bin&15)*4 within the u64 pair bin>>4
    unsigned long long inc = 1ull << ((unsigned)(bin << 2) & 63u);
    unsigned lo = (unsigned)inc;
    unsigned hi = (unsigned)(inc >> 32);
    int sel = bin >> 4;
#pragma unroll
    for (int k = 0; k < 4; ++k) {
        bool m = (sel == k);
        c[2 * k]     += m ? lo : 0u;
        c[2 * k + 1] += m ? hi : 0u;
    }
}

__device__ __forceinline__ void flushc(unsigned c[8], unsigned aLo[8], unsigned aHi[8]) {
#pragma unroll
    for (int r = 0; r < 8; ++r) {
        aLo[r] += c[r] & 0x0F0F0F0Fu;          // bins 8r+{0,2,4,6} as bytes
        aHi[r] += (c[r] >> 4) & 0x0F0F0F0Fu;   // bins 8r+{1,3,5,7} as bytes
        c[r] = 0u;
    }
}

__global__ __launch_bounds__(THREADS)
void hist_kernel(const float* __restrict__ fake,
                 const float* __restrict__ real,
                 unsigned int* __restrict__ partial) {
    __shared__ unsigned int trbuf[16 * TP];    // [word w][thread t] transposed
    __shared__ unsigned int comb[4][NBINS];

    const int tid  = threadIdx.x;
    const int lane = tid & 63;
    const int wv   = tid >> 6;

    const int b     = blockIdx.x;          // 0 .. 1535
    const int chunk = b & (BPR - 1);
    const int rowg  = b >> 3;              // 0..191: img*ROWS + row
    const float* src = (rowg < ROWS) ? fake : real;
    const int row    = (rowg < ROWS) ? rowg : (rowg - ROWS);

    const float4* __restrict__ p =
        (const float4*)(src + (size_t)row * HW + (size_t)chunk * CHUNK);

    unsigned c[8]   = {0, 0, 0, 0, 0, 0, 0, 0};   // 4-bit packed counters
    unsigned aLo[8] = {0, 0, 0, 0, 0, 0, 0, 0};   // byte accumulators (even bins)
    unsigned aHi[8] = {0, 0, 0, 0, 0, 0, 0, 0};   // byte accumulators (odd bins)

    // 10 groups of 3 float4 (12 elems < 16 -> nibbles can't overflow), rolled
    // outer loop to keep the body I-cache friendly.
#pragma unroll 1
    for (int g = 0; g < 10; ++g) {
#pragma unroll
        for (int j = 0; j < 3; ++j) {
            float4 v = p[(g * 3 + j) * THREADS + tid];
            bump(c, v.x); bump(c, v.y); bump(c, v.z); bump(c, v.w);
        }
        flushc(c, aLo, aHi);
    }
    // tail: iterations 30, 31 (8 elems) + final flush
#pragma unroll
    for (int j = 30; j < 32; ++j) {
        float4 v = p[j * THREADS + tid];
        bump(c, v.x); bump(c, v.y); bump(c, v.z); bump(c, v.w);
    }
    flushc(c, aLo, aHi);

    // ---- epilogue: transpose to LDS, then per-wave per-bin byte sums ----
    // word w<8  = aLo[w]  (bins 8w+{0,2,4,6}); w>=8 = aHi[w-8] (odd bins).
    // write: lanes t cover banks (4w+t)%32 -> 2/bank (free).
#pragma unroll
    for (int w = 0; w < 8; ++w) trbuf[w * TP + tid] = aLo[w];
#pragma unroll
    for (int w = 0; w < 8; ++w) trbuf[(w + 8) * TP + tid] = aHi[w];
    __syncthreads();

    // lane L reads word w(L), byte j(L) over its wave's 64 threads, b128 x16.
    // 16 distinct w across 64 lanes: 4 lanes/word broadcast, w vs w+8 2-way (free).
    const int w  = (lane >> 3) | ((lane & 1) << 3);
    const int sh = ((lane >> 1) & 3) * 8;
    unsigned cnt = 0;
#pragma unroll
    for (int t4 = 0; t4 < 16; ++t4) {
        const uint4 q = *(const uint4*)&trbuf[w * TP + wv * 64 + t4 * 4];
        cnt += (q.x >> sh) & 0xFFu;
        cnt += (q.y >> sh) & 0xFFu;
        cnt += (q.z >> sh) & 0xFFu;
        cnt += (q.w >> sh) & 0xFFu;
    }
    comb[wv][lane] = cnt;
    __syncthreads();

    if (tid < NBINS) {
        unsigned s = comb[0][tid] + comb[1][tid] + comb[2][tid] + comb[3][tid];
        partial[(size_t)b * NBINS + tid] = s;   // plain store, no global atomics
    }
}

__global__ __launch_bounds__(1024)
void loss_kernel(const unsigned int* __restrict__ partial,
                 float* __restrict__ out) {
    const int tid = threadIdx.x;
    int acc = 0;
#pragma unroll
    for (int q = 0; q < 6; ++q) {
        const int pIdx = q * 1024 + tid;     // 0..6143
        const int r  = pIdx >> 6;
        const int bb = pIdx & 63;
        unsigned cf = 0, cr = 0;
#pragma unroll
        for (int c = 0; c < BPR; ++c) {
            cf += partial[((r * BPR + c) * NBINS) + bb];
            cr += partial[(((ROWS + r) * BPR + c) * NBINS) + bb];
        }
        int d = (int)cf - (int)cr;
        acc += (d < 0) ? -d : d;
    }
#pragma unroll
    for (int off = 32; off > 0; off >>= 1)
        acc += __shfl_down(acc, off, 64);
    __shared__ int wsum[16];
    if ((tid & 63) == 0) wsum[tid >> 6] = acc;
    __syncthreads();
    if (tid == 0) {
        long long total = 0;
#pragma unroll
        for (int k = 0; k < 16; ++k) total += wsum[k];
        out[0] = (float)((double)total / (262144.0 * 6144.0));
    }
}

extern "C" void kernel_launch(void* const* d_in, const int* in_sizes, int n_in,
                              void* d_out, int out_size, void* d_ws, size_t ws_size,
                              hipStream_t stream) {
    const float* fake = (const float*)d_in[0];
    const float* real = (const float*)d_in[1];
    unsigned int* partial = (unsigned int*)d_ws;  // 1536*64 u32 = 393216 B
    float* out = (float*)d_out;

    hist_kernel<<<NBLOCKS, THREADS, 0, stream>>>(fake, real, partial);
    loss_kernel<<<1, 1024, 0, stream>>>(partial, out);
}